// Round 20
// baseline (110.870 us; speedup 1.0000x reference)
//
#include <hip/hip_runtime.h>

#define N_NODES 100000
#define N_EDGES 1600000
#define N_LABEL 200000
#define HID 128
#define OUT 5

#define NBUCK 391        // ceil(N_NODES/256) node buckets
#define EPB   4096       // edges per partition block
#define NBLK_E 391       // ceil(N_EDGES/EPB)
#define UBLKS 6250       // u-path blocks (16 nodes per block)

// ---------------------------------------------------------------------------
// Linear network: out[l] = proj[d][0..4] + proj[p][5..9] + b_lin,
//   u[n]    = x[n] @ G               (unscaled; computed overlapped with hist)
//   t[n]    = dinv_n * u[n]          (scaled in-place inside k_buildt)
//   proj[n] = dinv_n * (sum_{src} t[src] + t[n]) + c0
// with G = W_gcn @ [W_lin_top | W_lin_bot] (128x10), c0 = b_gcn @ W2.
// R20 = R16 base + {k_prep split out; x@G u-path fused into the hist dispatch
// as extra independent blocks (BW overlaps atomic latency, NO grid.sync);
// dinv-scale folded into k_build}.
// ---------------------------------------------------------------------------

// K_prep: G[r*16+j] (row 128 = c0 = b_gcn @ W2); also total=0. 9 blocks.
__global__ __launch_bounds__(256) void k_prep(const float* __restrict__ Wg,
                                              const float* __restrict__ bg,
                                              const float* __restrict__ Wl,
                                              float* __restrict__ G,
                                              int* __restrict__ total) {
    int o = blockIdx.x * 256 + threadIdx.x;
    if (o == 0) *total = 0;
    if (o >= 129 * 16) return;
    int r = o >> 4, jj = o & 15;
    float acc = 0.f;
    if (jj < 2 * OUT) {
        const int half = (jj >= OUT);
        const int j = half ? jj - OUT : jj;
        for (int c = 0; c < HID; ++c) {
            float w2 = Wl[(half * HID + c) * OUT + j];
            float a = (r < HID) ? Wg[r * HID + c] : bg[c];
            acc += a * w2;
        }
    }
    G[o] = acc;
}

// K_mega: blocks [0,NBLK_E) = dst-bucket histogram; blocks [NBLK_E,+UBLKS) =
// u[n] = x[n] @ G (16 lanes/node). Independent work, one dispatch: the 51.2MB
// x-stream overlaps the latency-bound histogram atomics.
__global__ __launch_bounds__(256) void k_mega(const int* __restrict__ ei,
                                              int* __restrict__ hist,
                                              const float* __restrict__ G,
                                              const float* __restrict__ x,
                                              float* __restrict__ u) {
    __shared__ char smraw[HID * 11 * 4];   // union: h[NBUCK] (1.6KB) / Gs (5.6KB)
    const int t = threadIdx.x, b = blockIdx.x;

    if (b >= NBLK_E) {   // ---- u path ----
        float* Gs = (float*)smraw;
        for (int o = t; o < HID * 10; o += 256) {
            int k = o / 10, j = o - k * 10;
            Gs[k * 11 + j] = G[k * 16 + j];
        }
        __syncthreads();

        int gid = (b - NBLK_E) * 256 + t;
        int n = gid >> 4;          // UBLKS*16 == N_NODES exactly
        int i = gid & 15;

        float xv[8];
#pragma unroll
        for (int m = 0; m < 8; ++m) xv[m] = x[(size_t)n * HID + i + 16 * m];

        float p[10];
#pragma unroll
        for (int j = 0; j < 10; ++j) p[j] = 0.f;
#pragma unroll
        for (int m = 0; m < 8; ++m) {
            const float* g = &Gs[(i + 16 * m) * 11];
#pragma unroll
            for (int j = 0; j < 10; ++j) p[j] += xv[m] * g[j];
        }
#pragma unroll
        for (int off = 1; off < 16; off <<= 1) {
#pragma unroll
            for (int j = 0; j < 10; ++j) p[j] += __shfl_xor(p[j], off);
        }
        float val = (i == 0) ? p[0] : (i == 1) ? p[1] : (i == 2) ? p[2] : (i == 3) ? p[3] :
                    (i == 4) ? p[4] : (i == 5) ? p[5] : (i == 6) ? p[6] : (i == 7) ? p[7] :
                    (i == 8) ? p[8] : (i == 9) ? p[9] : 0.f;
        u[(size_t)n * 16 + i] = val;
        return;
    }

    // ---- hist path ----
    int* h = (int*)smraw;
    for (int i = t; i < NBUCK; i += 256) h[i] = 0;
    __syncthreads();
    const int e0 = b * EPB;
#pragma unroll
    for (int i = 0; i < 16; ++i) {
        int e = e0 + i * 256 + t;
        if (e < N_EDGES) atomicAdd(&h[ei[N_EDGES + e] >> 8], 1);
    }
    __syncthreads();
    for (int i = t; i < NBUCK; i += 256) hist[i * NBLK_E + b] = h[i];
}

// K_scanb: per-bucket scan over 391 block entries + atomic-ticket bucket base.
__global__ __launch_bounds__(256) void k_scanb(int* __restrict__ hist,
                                               int* __restrict__ btot,
                                               int* __restrict__ bbase,
                                               int* __restrict__ total) {
    __shared__ int part[256];
    const int b = blockIdx.x, t = threadIdx.x;
    int* row = hist + b * NBLK_E;
    const int lo = t * 2, hi = min(lo + 2, NBLK_E);
    int v[2]; int s = 0;
    for (int i = lo; i < hi; ++i) { v[i - lo] = row[i]; s += v[i - lo]; }
    part[t] = s;
    __syncthreads();
#pragma unroll
    for (int off = 1; off < 256; off <<= 1) {
        int a = (t >= off) ? part[t - off] : 0;
        __syncthreads();
        part[t] += a;
        __syncthreads();
    }
    int run = part[t] - s;
    for (int i = lo; i < hi; ++i) { int x = v[i - lo]; row[i] = run; run += x; }
    if (t == 255) {
        int tot = part[255];
        btot[b] = tot;
        bbase[b] = atomicAdd(total, tot);   // disjoint range ticket
    }
}

// K_part: partition edges into bucket regions. bedge = src | (dst&255)<<20.
__global__ __launch_bounds__(256) void k_part(const int* __restrict__ ei,
                                              const int* __restrict__ hist,
                                              const int* __restrict__ bbase,
                                              unsigned* __restrict__ bedge) {
    __shared__ int cur[NBUCK];
    const int t = threadIdx.x, b = blockIdx.x;
    for (int i = t; i < NBUCK; i += 256) cur[i] = bbase[i] + hist[i * NBLK_E + b];
    __syncthreads();
    const int e0 = b * EPB;
#pragma unroll
    for (int i = 0; i < 16; ++i) {
        int e = e0 + i * 256 + t;
        if (e < N_EDGES) {
            int dst = ei[N_EDGES + e];
            unsigned src = (unsigned)ei[e];
            int pos = atomicAdd(&cur[dst >> 8], 1);
            bedge[pos] = src | ((unsigned)(dst & 255) << 20);
        }
    }
}

// K_buildt: per-bucket CSR (LDS count/scan/rank) -> csr, seg, dinv,
//   PLUS in-place scale of this bucket's t rows: t[n] = rsqrt(cnt+1)*u[n].
__global__ __launch_bounds__(256) void k_buildt(const unsigned* __restrict__ bedge,
                                                const int* __restrict__ bbase,
                                                const int* __restrict__ btot,
                                                int* __restrict__ csr,
                                                int2* __restrict__ seg,
                                                float* __restrict__ dinv,
                                                float* __restrict__ tu) {
    __shared__ int cnt[256];
    __shared__ int nb[256];
    __shared__ int cursor[256];
    const int b = blockIdx.x, t = threadIdx.x;
    const int base = bbase[b];
    const int size = btot[b];
    cnt[t] = 0;
    __syncthreads();
    for (int i = t; i < size; i += 256) atomicAdd(&cnt[bedge[base + i] >> 20], 1);
    __syncthreads();
    const int c = cnt[t];
    nb[t] = c;
    __syncthreads();
#pragma unroll
    for (int off = 1; off < 256; off <<= 1) {
        int a = (t >= off) ? nb[t - off] : 0;
        __syncthreads();
        nb[t] += a;
        __syncthreads();
    }
    const int myBase = nb[t] - c;
    cursor[t] = myBase;
    __syncthreads();
    for (int i = t; i < size; i += 256) {
        unsigned v = bedge[base + i];
        int pos = atomicAdd(&cursor[v >> 20], 1);
        csr[base + pos] = (int)(v & 0xFFFFFu);
    }
    const int n = b * 256 + t;
    if (n < N_NODES) {
        seg[n] = make_int2(base + myBase, c);
        dinv[n] = rsqrtf((float)(c + 1));
    }
    // in-place scale: t rows of this bucket (flat coalesced; cnt[] intact)
    const size_t fb = (size_t)b * 256 * 16;
    for (int f = t; f < 256 * 16; f += 256) {
        int nl = f >> 4;
        if (b * 256 + nl < N_NODES)
            tu[fb + f] = rsqrtf((float)(cnt[nl] + 1)) * tu[fb + f];
    }
}

// K_pullt: proj[n] = dinv[n]*(sum_src t[src] + t[n]) + c0.
__global__ __launch_bounds__(256) void k_pullt(const float* __restrict__ t,
                                               const int2* __restrict__ seg,
                                               const int* __restrict__ csr,
                                               const float* __restrict__ dinv,
                                               const float* __restrict__ G,
                                               float* __restrict__ proj) {
    int gid = blockIdx.x * 256 + threadIdx.x;
    int n = gid >> 4;
    int i = gid & 15;
    const int gbase = threadIdx.x & 48;   // 16-lane group base within wave

    float acc = t[(size_t)n * 16 + i];    // self term
    const int2 sg = seg[n];
    const int beg = sg.x, deg = sg.y;

    for (int base = 0; base < deg; base += 16) {
        const int cnt = min(16, deg - base);
        int idx = (i < cnt) ? csr[beg + base + i] : 0;
        int j = 0;
        for (; j + 4 <= cnt; j += 4) {
            int s0 = __shfl(idx, gbase + j);
            int s1 = __shfl(idx, gbase + j + 1);
            int s2 = __shfl(idx, gbase + j + 2);
            int s3 = __shfl(idx, gbase + j + 3);
            float v0 = t[(size_t)s0 * 16 + i];
            float v1 = t[(size_t)s1 * 16 + i];
            float v2 = t[(size_t)s2 * 16 + i];
            float v3 = t[(size_t)s3 * 16 + i];
            acc += v0; acc += v1; acc += v2; acc += v3;
        }
        for (; j < cnt; ++j) {
            int s = __shfl(idx, gbase + j);
            acc += t[(size_t)s * 16 + i];
        }
    }
    proj[(size_t)n * 16 + i] = dinv[n] * acc + G[HID * 16 + i];   // + c0
}

// K_link: dense mapping — one thread per output element.
__global__ __launch_bounds__(256) void k_link2(const int* __restrict__ eli,
                                               const float* __restrict__ proj,
                                               const float* __restrict__ bl,
                                               float* __restrict__ out) {
    int idx = blockIdx.x * 256 + threadIdx.x;
    if (idx >= N_LABEL * OUT) return;
    int l = idx / OUT;
    int o = idx - l * OUT;
    int d = eli[l];
    int p = eli[N_LABEL + l];
    out[idx] = proj[d * 16 + o] + proj[p * 16 + OUT + o] + bl[o];
}

// ---------------------------------------------------------------------------
extern "C" void kernel_launch(void* const* d_in, const int* in_sizes, int n_in,
                              void* d_out, int out_size, void* d_ws, size_t ws_size,
                              hipStream_t stream) {
    const float* x     = (const float*)d_in[0];
    const int*   ei    = (const int*)d_in[1];
    const int*   eli   = (const int*)d_in[2];
    const float* W_gcn = (const float*)d_in[3];
    const float* b_gcn = (const float*)d_in[4];
    const float* W_lin = (const float*)d_in[5];
    const float* b_lin = (const float*)d_in[6];
    float* out = (float*)d_out;

    // workspace layout (tu = u, then scaled in-place to t)
    float* tu        = (float*)d_ws;                           // 100k x 16 f32 (6.4 MB)
    float* proj      = tu + (size_t)N_NODES * 16;              // 100k x 16 f32 (6.4 MB)
    float* G         = proj + (size_t)N_NODES * 16;            // 129*16 f32
    float* dinv      = G + 129 * 16;                           // 100k f32
    unsigned* bedge  = (unsigned*)(dinv + N_NODES);            // 1.6M u32 (6.4 MB)
    int*   csr       = (int*)(bedge + N_EDGES);                // 1.6M int (6.4 MB)
    int2*  seg       = (int2*)(csr + N_EDGES);                 // 100k int2
    int*   hist      = (int*)(seg + N_NODES);                  // 391*391 int (0.6 MB)
    int*   btot      = hist + NBUCK * NBLK_E;                  // 391 int
    int*   bbase     = btot + NBUCK;                           // 391 int
    int*   total     = bbase + NBUCK;                          // 1 int

    // G + c0 precompute + ticket reset (u-path consumes G, so separate dispatch)
    k_prep<<<9, 256, 0, stream>>>(W_gcn, b_gcn, W_lin, G, total);
    // histogram + u = x @ G in ONE dispatch (BW overlaps atomic latency)
    k_mega<<<NBLK_E + UBLKS, 256, 0, stream>>>(ei, hist, G, x, tu);
    // per-bucket scan + atomic-ticket bases
    k_scanb<<<NBUCK, 256, 0, stream>>>(hist, btot, bbase, total);
    // partition edges into buckets
    k_part<<<NBLK_E, 256, 0, stream>>>(ei, hist, bbase, bedge);
    // per-bucket CSR + seg + dinv + in-place t scale
    k_buildt<<<NBUCK, 256, 0, stream>>>(bedge, bbase, btot, csr, seg, dinv, tu);
    // proj = dinv * (sum t[src] + t[n]) + c0
    k_pullt<<<N_NODES * 16 / 256, 256, 0, stream>>>(tu, seg, csr, dinv, G, proj);
    // out = gather-add (dense mapping)
    k_link2<<<(N_LABEL * OUT + 255) / 256, 256, 0, stream>>>(eli, proj, b_lin, out);
}

// Round 21
// 106.259 us; speedup vs baseline: 1.0434x; 1.0434x over previous
//
#include <hip/hip_runtime.h>

#define N_NODES 100000
#define N_EDGES 1600000
#define N_LABEL 200000
#define HID 128
#define OUT 5

#define NBUCK 391        // ceil(N_NODES/256) node buckets
#define EPB   4096       // edges per partition block
#define NBLK_E 391       // ceil(N_EDGES/EPB)
#define PREC_BLKS 9      // ceil(129*16/256) precomp blocks appended to k_hist

// ---------------------------------------------------------------------------
// Linear network: out[l] = proj[d][0..4] + proj[p][5..9] + b_lin,
//   t[n]    = dinv_n * (x[n] @ G)            (fp32, 16-col padded, 64B row)
//   proj[n] = dinv_n * (sum_{src} t[src] + t[n]) + c0
// with G = W_gcn @ [W_lin_top | W_lin_bot] (128x10), c0 = b_gcn @ W2.
// R21 = exact R16/R19 source (measured best: 106.4 / 106.5 us, reproduced).
// Failed directions (all measured): bf16 t-rows (R12/R13), LDS-atomic
// edge-parallel accum (R14), cooperative CSR fusion (R18), hist+u overlap
// dispatch (R20). Wins that built this: CSR-pull vs atomic scatter (R2),
// ticket-allocator scan (R3), atomic-free 2-level CSR (R9), algebraic
// linearization G = W_gcn @ W2 (R11), EPB=4096 + dense link (R16).
// ---------------------------------------------------------------------------

// K_hist (+ merged precomp): blocks < NBLK_E histogram dst buckets;
// blocks >= NBLK_E compute G (row 128 = c0 = b_gcn @ W2); also total=0.
__global__ __launch_bounds__(256) void k_hist(const int* __restrict__ ei,
                                              int* __restrict__ hist,
                                              const float* __restrict__ Wg,
                                              const float* __restrict__ bg,
                                              const float* __restrict__ Wl,
                                              float* __restrict__ G,
                                              int* __restrict__ total) {
    const int t = threadIdx.x, b = blockIdx.x;
    if (b >= NBLK_E) {   // precomp path (whole block)
        if (b == NBLK_E && t == 0) *total = 0;   // ticket counter reset
        int o = (b - NBLK_E) * 256 + t;
        if (o < 129 * 16) {
            int r = o >> 4, jj = o & 15;
            float acc = 0.f;
            if (jj < 2 * OUT) {
                const int half = (jj >= OUT);
                const int j = half ? jj - OUT : jj;
                for (int c = 0; c < HID; ++c) {
                    float w2 = Wl[(half * HID + c) * OUT + j];
                    float a = (r < HID) ? Wg[r * HID + c] : bg[c];
                    acc += a * w2;
                }
            }
            G[o] = acc;
        }
        return;
    }
    __shared__ int h[NBUCK];
    for (int i = t; i < NBUCK; i += 256) h[i] = 0;
    __syncthreads();
    const int e0 = b * EPB;
#pragma unroll
    for (int i = 0; i < 16; ++i) {
        int e = e0 + i * 256 + t;
        if (e < N_EDGES) atomicAdd(&h[ei[N_EDGES + e] >> 8], 1);
    }
    __syncthreads();
    for (int i = t; i < NBUCK; i += 256) hist[i * NBLK_E + b] = h[i];
}

// K_scanb: per-bucket scan over 391 block entries + atomic-ticket bucket base.
__global__ __launch_bounds__(256) void k_scanb(int* __restrict__ hist,
                                               int* __restrict__ btot,
                                               int* __restrict__ bbase,
                                               int* __restrict__ total) {
    __shared__ int part[256];
    const int b = blockIdx.x, t = threadIdx.x;
    int* row = hist + b * NBLK_E;
    const int lo = t * 2, hi = min(lo + 2, NBLK_E);
    int v[2]; int s = 0;
    for (int i = lo; i < hi; ++i) { v[i - lo] = row[i]; s += v[i - lo]; }
    part[t] = s;
    __syncthreads();
#pragma unroll
    for (int off = 1; off < 256; off <<= 1) {
        int a = (t >= off) ? part[t - off] : 0;
        __syncthreads();
        part[t] += a;
        __syncthreads();
    }
    int run = part[t] - s;
    for (int i = lo; i < hi; ++i) { int x = v[i - lo]; row[i] = run; run += x; }
    if (t == 255) {
        int tot = part[255];
        btot[b] = tot;
        bbase[b] = atomicAdd(total, tot);   // disjoint range ticket
    }
}

// K_part: partition edges into bucket regions. bedge = src | (dst&255)<<20.
__global__ __launch_bounds__(256) void k_part(const int* __restrict__ ei,
                                              const int* __restrict__ hist,
                                              const int* __restrict__ bbase,
                                              unsigned* __restrict__ bedge) {
    __shared__ int cur[NBUCK];
    const int t = threadIdx.x, b = blockIdx.x;
    for (int i = t; i < NBUCK; i += 256) cur[i] = bbase[i] + hist[i * NBLK_E + b];
    __syncthreads();
    const int e0 = b * EPB;
#pragma unroll
    for (int i = 0; i < 16; ++i) {
        int e = e0 + i * 256 + t;
        if (e < N_EDGES) {
            int dst = ei[N_EDGES + e];
            unsigned src = (unsigned)ei[e];
            int pos = atomicAdd(&cur[dst >> 8], 1);
            bedge[pos] = src | ((unsigned)(dst & 255) << 20);
        }
    }
}

// K_build: per-bucket CSR (LDS count/scan/rank) -> csr, seg, dinv.
__global__ __launch_bounds__(256) void k_build(const unsigned* __restrict__ bedge,
                                               const int* __restrict__ bbase,
                                               const int* __restrict__ btot,
                                               int* __restrict__ csr,
                                               int2* __restrict__ seg,
                                               float* __restrict__ dinv) {
    __shared__ int cnt[256];
    __shared__ int nb[256];
    __shared__ int cursor[256];
    const int b = blockIdx.x, t = threadIdx.x;
    const int base = bbase[b];
    const int size = btot[b];
    cnt[t] = 0;
    __syncthreads();
    for (int i = t; i < size; i += 256) atomicAdd(&cnt[bedge[base + i] >> 20], 1);
    __syncthreads();
    const int c = cnt[t];
    nb[t] = c;
    __syncthreads();
#pragma unroll
    for (int off = 1; off < 256; off <<= 1) {
        int a = (t >= off) ? nb[t - off] : 0;
        __syncthreads();
        nb[t] += a;
        __syncthreads();
    }
    const int myBase = nb[t] - c;
    cursor[t] = myBase;
    __syncthreads();
    for (int i = t; i < size; i += 256) {
        unsigned v = bedge[base + i];
        int pos = atomicAdd(&cursor[v >> 20], 1);
        csr[base + pos] = (int)(v & 0xFFFFFu);
    }
    const int n = b * 256 + t;
    if (n < N_NODES) {
        seg[n] = make_int2(base + myBase, c);
        dinv[n] = rsqrtf((float)(c + 1));
    }
}

// K_t: t[n][0..9] = dinv[n] * (x[n] @ G), rows padded to 16 (cols 10-15 = 0).
__global__ __launch_bounds__(256) void k_t(const float* __restrict__ x,
                                           const float* __restrict__ G,
                                           const float* __restrict__ dinv,
                                           float* __restrict__ t) {
    __shared__ float Gs[HID * 11];
    const int tid = threadIdx.x;
    for (int o = tid; o < HID * 10; o += 256) {
        int k = o / 10, j = o - k * 10;
        Gs[k * 11 + j] = G[k * 16 + j];
    }
    __syncthreads();

    int gid = blockIdx.x * 256 + tid;
    int n = gid >> 4;
    int i = gid & 15;

    float xv[8];
#pragma unroll
    for (int m = 0; m < 8; ++m) xv[m] = x[(size_t)n * HID + i + 16 * m];

    float p[10];
#pragma unroll
    for (int j = 0; j < 10; ++j) p[j] = 0.f;
#pragma unroll
    for (int m = 0; m < 8; ++m) {
        const float* g = &Gs[(i + 16 * m) * 11];
#pragma unroll
        for (int j = 0; j < 10; ++j) p[j] += xv[m] * g[j];
    }
#pragma unroll
    for (int off = 1; off < 16; off <<= 1) {
#pragma unroll
        for (int j = 0; j < 10; ++j) p[j] += __shfl_xor(p[j], off);
    }
    float val = (i == 0) ? p[0] : (i == 1) ? p[1] : (i == 2) ? p[2] : (i == 3) ? p[3] :
                (i == 4) ? p[4] : (i == 5) ? p[5] : (i == 6) ? p[6] : (i == 7) ? p[7] :
                (i == 8) ? p[8] : (i == 9) ? p[9] : 0.f;
    t[(size_t)n * 16 + i] = dinv[n] * val;
}

// K_pullt: proj[n] = dinv[n]*(sum_src t[src] + t[n]) + c0.
__global__ __launch_bounds__(256) void k_pullt(const float* __restrict__ t,
                                               const int2* __restrict__ seg,
                                               const int* __restrict__ csr,
                                               const float* __restrict__ dinv,
                                               const float* __restrict__ G,
                                               float* __restrict__ proj) {
    int gid = blockIdx.x * 256 + threadIdx.x;
    int n = gid >> 4;
    int i = gid & 15;
    const int gbase = threadIdx.x & 48;   // 16-lane group base within wave

    float acc = t[(size_t)n * 16 + i];    // self term
    const int2 sg = seg[n];
    const int beg = sg.x, deg = sg.y;

    for (int base = 0; base < deg; base += 16) {
        const int cnt = min(16, deg - base);
        int idx = (i < cnt) ? csr[beg + base + i] : 0;
        int j = 0;
        for (; j + 4 <= cnt; j += 4) {
            int s0 = __shfl(idx, gbase + j);
            int s1 = __shfl(idx, gbase + j + 1);
            int s2 = __shfl(idx, gbase + j + 2);
            int s3 = __shfl(idx, gbase + j + 3);
            float v0 = t[(size_t)s0 * 16 + i];
            float v1 = t[(size_t)s1 * 16 + i];
            float v2 = t[(size_t)s2 * 16 + i];
            float v3 = t[(size_t)s3 * 16 + i];
            acc += v0; acc += v1; acc += v2; acc += v3;
        }
        for (; j < cnt; ++j) {
            int s = __shfl(idx, gbase + j);
            acc += t[(size_t)s * 16 + i];
        }
    }
    proj[(size_t)n * 16 + i] = dinv[n] * acc + G[HID * 16 + i];   // + c0
}

// K_link: dense mapping — one thread per output element.
__global__ __launch_bounds__(256) void k_link2(const int* __restrict__ eli,
                                               const float* __restrict__ proj,
                                               const float* __restrict__ bl,
                                               float* __restrict__ out) {
    int idx = blockIdx.x * 256 + threadIdx.x;
    if (idx >= N_LABEL * OUT) return;
    int l = idx / OUT;
    int o = idx - l * OUT;
    int d = eli[l];
    int p = eli[N_LABEL + l];
    out[idx] = proj[d * 16 + o] + proj[p * 16 + OUT + o] + bl[o];
}

// ---------------------------------------------------------------------------
extern "C" void kernel_launch(void* const* d_in, const int* in_sizes, int n_in,
                              void* d_out, int out_size, void* d_ws, size_t ws_size,
                              hipStream_t stream) {
    const float* x     = (const float*)d_in[0];
    const int*   ei    = (const int*)d_in[1];
    const int*   eli   = (const int*)d_in[2];
    const float* W_gcn = (const float*)d_in[3];
    const float* b_gcn = (const float*)d_in[4];
    const float* W_lin = (const float*)d_in[5];
    const float* b_lin = (const float*)d_in[6];
    float* out = (float*)d_out;

    // workspace layout
    float* t         = (float*)d_ws;                           // 100k x 16 f32 (6.4 MB)
    float* proj      = t + (size_t)N_NODES * 16;               // 100k x 16 f32 (6.4 MB)
    float* G         = proj + (size_t)N_NODES * 16;            // 129*16 f32
    float* dinv      = G + 129 * 16;                           // 100k f32
    unsigned* bedge  = (unsigned*)(dinv + N_NODES);            // 1.6M u32 (6.4 MB)
    int*   csr       = (int*)(bedge + N_EDGES);                // 1.6M int (6.4 MB)
    int2*  seg       = (int2*)(csr + N_EDGES);                 // 100k int2
    int*   hist      = (int*)(seg + N_NODES);                  // 391*391 int (0.6 MB)
    int*   btot      = hist + NBUCK * NBLK_E;                  // 391 int
    int*   bbase     = btot + NBUCK;                           // 391 int
    int*   total     = bbase + NBUCK;                          // 1 int

    // histogram + (merged) G/c0 precompute + total reset
    k_hist<<<NBLK_E + PREC_BLKS, 256, 0, stream>>>(ei, hist, W_gcn, b_gcn, W_lin, G, total);
    // per-bucket scan + atomic-ticket bases
    k_scanb<<<NBUCK, 256, 0, stream>>>(hist, btot, bbase, total);
    // partition edges into buckets
    k_part<<<NBLK_E, 256, 0, stream>>>(ei, hist, bbase, bedge);
    // per-bucket CSR + seg + dinv
    k_build<<<NBUCK, 256, 0, stream>>>(bedge, bbase, btot, csr, seg, dinv);
    // t = dinv * (x @ G)
    k_t<<<N_NODES * 16 / 256, 256, 0, stream>>>(x, G, dinv, t);
    // proj = dinv * (sum t[src] + t[n]) + c0
    k_pullt<<<N_NODES * 16 / 256, 256, 0, stream>>>(t, seg, csr, dinv, G, proj);
    // out = gather-add (dense mapping)
    k_link2<<<(N_LABEL * OUT + 255) / 256, 256, 0, stream>>>(eli, proj, b_lin, out);
}